// Round 10
// baseline (33.142 us; speedup 1.0000x reference)
//
#include <hip/hip_runtime.h>
#include <math.h>

// LightconvLayer: x (T,B,C) f32, weight (H,K) f32 -> out (T,B,C) f32
// out[t,b,c] = sum_k softmax(weight[c/64])[k] * x[t+k-30, b, c] (zero-pad left)
//
// R10 = R8 (wave-autonomous, depth-2 counted vmcnt, no barriers) +
//   (a) CHUNK 128->64: 4096 one-wave blocks = 16 waves/CU (2x R8 streams)
//   (b) sliding REGISTER window xv[38]: halo loaded once to regs in prologue,
//       each staged row ds_read exactly ONCE (8/tile vs R8's 38/tile);
//       full unroll -> window shift is pure register renaming
//   (c) ring shrinks to 32 rows x 64 ch = 8 KB -> LDS no longer caps occupancy
// vmcnt (in-order, NTILE=8): j0=4, j1=12, j2..5=20, j6=18, j7=16.
// Slot safety mod 32: stage(j+2) -> (8j+16..23)&31, live reads (8j..8j+15)&31
// disjoint; same-slot predecessor load L(j-2) retired at tile j-2's wait.
#define T_LEN 2048
#define B_SZ  8
#define C_SZ  1024
#define NH    16
#define KW    31
#define HALO  (KW - 1)        // 30
#define TT    8
#define CHUNK 64              // rows per wave
#define NTILE (CHUNK / TT)    // 8
#define RING  32
#define WIN   (TT + HALO)     // 38
#define ROWSTRIDE (B_SZ * C_SZ)  // 8192 floats between t rows

#define GLOBAL_AS(p) ((const __attribute__((address_space(1))) void*)(p))
#define LDS_AS(p)    ((__attribute__((address_space(3))) void*)(p))

__global__ __launch_bounds__(64, 4) void lightconv_kernel(
    const float* __restrict__ x, const float* __restrict__ weight,
    float* __restrict__ out) {
  __shared__ float ring[RING][64];   // 8 KB, wave-private (1 wave/block)
  const int lane = threadIdx.x;

  const int cgrp = blockIdx.x & 15;  // head (C/64 = 16 = NH)
  const int tc   = blockIdx.x >> 4;  // t-chunk 0..31
  const int b    = blockIdx.y;
  const int c0   = cgrp * 64;
  const int tb   = tc * CHUNK;       // tb % 32 == 0 -> compile-time slots

  // --- taps: uniform loads -> uniform softmax -> SGPR via readfirstlane ---
  float wv[KW];
  float m = -1e30f;
#pragma unroll
  for (int k = 0; k < KW; ++k) {
    wv[k] = weight[cgrp * KW + k];
    m = fmaxf(m, wv[k]);
  }
  float s = 0.f;
#pragma unroll
  for (int k = 0; k < KW; ++k) {
    wv[k] = expf(wv[k] - m);
    s += wv[k];
  }
  const float inv = 1.f / s;
  float wk[KW];
#pragma unroll
  for (int k = 0; k < KW; ++k) {
    wk[k] = __uint_as_float(
        __builtin_amdgcn_readfirstlane(__float_as_uint(wv[k] * inv)));
  }

  const float* xbase = x + (size_t)b * C_SZ + c0;
  // width-16 staging: lane l -> row (l>>4), ch (l&15)*4; 1 instr = 4 ring rows
  const int lane_off = (lane >> 4) * ROWSTRIDE + (lane & 15) * 4;  // floats

  // --- prologue ---
  // halo rows tb-30..tb-1 -> registers xv[0..29] (single use, no LDS)
  float xv[WIN];
  if (tb == 0) {
#pragma unroll
    for (int i = 0; i < HALO; ++i) xv[i] = 0.f;
  } else {
#pragma unroll
    for (int i = 0; i < HALO; ++i) {
      xv[i] = xbase[(size_t)(tb - HALO + i) * ROWSTRIDE + lane];
    }
  }
  // stage L(0): rows tb..tb+7 -> slots 0..7; L(1): rows tb+8..15 -> slots 8..15
#pragma unroll
  for (int r4 = 0; r4 < 4; ++r4) {
    const float* gp = xbase + (size_t)(tb + 4 * r4) * ROWSTRIDE + lane_off;
    __builtin_amdgcn_global_load_lds(GLOBAL_AS(gp), LDS_AS(&ring[4 * r4][0]),
                                     16, 0, 0);
  }

  // --- 8 tiles, fully unrolled, no barriers, counted own-vmcnt ---
#pragma unroll
  for (int j = 0; j < NTILE; ++j) {
    const int tstart = tb + j * TT;

    // stage L(j+2): rows tstart+16..23 -> slots (8j+16+4r4)&31 (compile-time)
    if (j <= NTILE - 3) {
#pragma unroll
      for (int r4 = 0; r4 < 2; ++r4) {
        const float* gp =
            xbase + (size_t)(tstart + 2 * TT + 4 * r4) * ROWSTRIDE + lane_off;
        __builtin_amdgcn_global_load_lds(
            GLOBAL_AS(gp), LDS_AS(&ring[(8 * j + 16 + 4 * r4) & (RING - 1)][0]),
            16, 0, 0);
      }
    }
    // counted wait: guarantee L(j) retired (in-order vmem retirement)
    if (j == 0)                asm volatile("s_waitcnt vmcnt(4)"  ::: "memory");
    else if (j == 1)           asm volatile("s_waitcnt vmcnt(12)" ::: "memory");
    else if (j == NTILE - 2)   asm volatile("s_waitcnt vmcnt(18)" ::: "memory");
    else if (j == NTILE - 1)   asm volatile("s_waitcnt vmcnt(16)" ::: "memory");
    else                       asm volatile("s_waitcnt vmcnt(20)" ::: "memory");
    __builtin_amdgcn_sched_barrier(0);  // rule #18: pin ds_reads below

    // read tile j's 8 NEW rows once: slots (8j+i)&31 -> xv[30..37]
#pragma unroll
    for (int i = 0; i < TT; ++i) {
      xv[HALO + i] = ring[(8 * j + i) & (RING - 1)][lane];
    }
    // compute + store 8 outputs
    float* op = out + ((size_t)tstart * B_SZ + b) * C_SZ + c0 + lane;
#pragma unroll
    for (int o = 0; o < TT; ++o) {
      float a = 0.f;
#pragma unroll
      for (int k = 0; k < KW; ++k) a = fmaf(wk[k], xv[o + k], a);
      op[(size_t)o * ROWSTRIDE] = a;
    }
    // slide window by TT (full unroll -> pure renaming, no v_mov cost)
#pragma unroll
    for (int i = 0; i < HALO; ++i) xv[i] = xv[i + TT];
  }
}

extern "C" void kernel_launch(void* const* d_in, const int* in_sizes, int n_in,
                              void* d_out, int out_size, void* d_ws, size_t ws_size,
                              hipStream_t stream) {
  const float* x = (const float*)d_in[0];      // (T,B,C) f32
  const float* w = (const float*)d_in[1];      // (H,K) f32
  float* out = (float*)d_out;                  // (T,B,C) f32
  (void)in_sizes; (void)n_in; (void)out_size; (void)d_ws; (void)ws_size;

  dim3 grid((C_SZ / 64) * (T_LEN / CHUNK), B_SZ);  // (512, 8) = 4096 waves
  dim3 block(64);
  lightconv_kernel<<<grid, block, 0, stream>>>(x, w, out);
}

// Round 11
// 30.176 us; speedup vs baseline: 1.0983x; 1.0983x over previous
//
#include <hip/hip_runtime.h>
#include <math.h>

// LightconvLayer: x (T,B,C) f32, weight (H,K) f32 -> out (T,B,C) f32
// out[t,b,c] = sum_k softmax(weight[c/64])[k] * x[t+k-30, b, c] (zero-pad left)
//
// R11 = R8 skeleton (wave-autonomous, depth-2 counted vmcnt, no barriers),
// widened to 2 channels/lane (H5 test: store width 4B -> 8B/lane):
//  - wave owns (b, 128 ch = 2 heads, 64-row chunk); 8 tiles of TT=8
//  - stores: global_store_dwordx2 (512 B/instr, 2x R8)
//  - staging: width-16 gload_lds packs 2 rows/instr (lane l -> row l>>5,
//    ch (l&31)*4); 4 instrs per 8-row tile
//  - halo -> registers (30 x dwordx2), sliding window xv[38] of float2
//  - taps per-lane VGPR (2 heads/wave, no readfirstlane)
// vmcnt ledger (in-order, loads+stores): j0=8, j1=16, j2..5=24, j6=20, j7=16
// slot safety mod 32: stage(j+2) slots (8j+16..23)&31 vs reads (8j..8j+7)&31
#define T_LEN 2048
#define B_SZ  8
#define C_SZ  1024
#define NH    16
#define KW    31
#define HALO  (KW - 1)        // 30
#define TT    8
#define CHUNK 64              // rows per wave
#define NTILE (CHUNK / TT)    // 8
#define RING  32
#define WIN   (TT + HALO)     // 38
#define CGW   128             // channels per wave
#define ROWSTRIDE (B_SZ * C_SZ)  // 8192 floats between t rows

#define GLOBAL_AS(p) ((const __attribute__((address_space(1))) void*)(p))
#define LDS_AS(p)    ((__attribute__((address_space(3))) void*)(p))

__global__ __launch_bounds__(64, 3) void lightconv_kernel(
    const float* __restrict__ x, const float* __restrict__ weight,
    float* __restrict__ out) {
  __shared__ float ring[RING][CGW];  // 16 KB, wave-private (1 wave/block)
  const int lane = threadIdx.x;

  const int cgrp = blockIdx.x & 7;   // 128-ch group (C/128 = 8)
  const int tc   = blockIdx.x >> 3;  // t-chunk 0..31
  const int b    = blockIdx.y;
  const int c0   = cgrp * CGW;
  const int tb   = tc * CHUNK;       // tb % 32 == 0 -> compile-time slots

  // --- taps: per-lane (2 heads per wave). load + softmax in VGPRs ---
  const int head = cgrp * 2 + (lane >> 5);
  float wv[KW];
  float m = -1e30f;
#pragma unroll
  for (int k = 0; k < KW; ++k) {
    wv[k] = weight[head * KW + k];
    m = fmaxf(m, wv[k]);
  }
  float s = 0.f;
#pragma unroll
  for (int k = 0; k < KW; ++k) {
    wv[k] = expf(wv[k] - m);
    s += wv[k];
  }
  const float inv = 1.f / s;
  float wk[KW];
#pragma unroll
  for (int k = 0; k < KW; ++k) wk[k] = wv[k] * inv;

  const float* xbase = x + (size_t)b * C_SZ + c0;
  const float* xch   = xbase + 2 * lane;  // per-lane channel pair base
  // staging offset: lane l -> row (l>>5), ch (l&31)*4 floats (16 B)
  const int lane_off = (lane >> 5) * ROWSTRIDE + (lane & 31) * 4;

  // --- prologue ---
  // halo rows tb-30..tb-1 -> registers xv[0..29] (float2, 512 B/instr)
  float2 xv[WIN];
  if (tb == 0) {
#pragma unroll
    for (int i = 0; i < HALO; ++i) xv[i] = make_float2(0.f, 0.f);
  } else {
#pragma unroll
    for (int i = 0; i < HALO; ++i) {
      xv[i] = *(const float2*)&xch[(size_t)(tb - HALO + i) * ROWSTRIDE];
    }
  }
  // stage L(0): rows tb..tb+7 -> slots 0..7; L(1): rows tb+8..15 -> slots 8..15
  // (each width-16 instr = 2 full 512 B rows = 1 KB contiguous)
#pragma unroll
  for (int r2 = 0; r2 < 8; ++r2) {
    const float* gp = xbase + (size_t)(tb + 2 * r2) * ROWSTRIDE + lane_off;
    __builtin_amdgcn_global_load_lds(GLOBAL_AS(gp), LDS_AS(&ring[2 * r2][0]),
                                     16, 0, 0);
  }

  // --- 8 tiles, fully unrolled, no barriers, counted own-vmcnt ---
#pragma unroll
  for (int j = 0; j < NTILE; ++j) {
    const int tstart = tb + j * TT;

    // stage L(j+2): rows tstart+16..23 -> slots (8j+16+2r2)&31 (compile-time)
    if (j <= NTILE - 3) {
#pragma unroll
      for (int r2 = 0; r2 < 4; ++r2) {
        const float* gp =
            xbase + (size_t)(tstart + 2 * TT + 2 * r2) * ROWSTRIDE + lane_off;
        __builtin_amdgcn_global_load_lds(
            GLOBAL_AS(gp), LDS_AS(&ring[(8 * j + 16 + 2 * r2) & (RING - 1)][0]),
            16, 0, 0);
      }
    }
    // counted wait: guarantee L(j) retired (in-order vmem retirement;
    // ledger: newer-than-L(j) = S(j-2)8 + L(j+1)4 + S(j-1)8 + L(j+2)4 = 24)
    if (j == 0)                asm volatile("s_waitcnt vmcnt(8)"  ::: "memory");
    else if (j == 1)           asm volatile("s_waitcnt vmcnt(16)" ::: "memory");
    else if (j == NTILE - 2)   asm volatile("s_waitcnt vmcnt(20)" ::: "memory");
    else if (j == NTILE - 1)   asm volatile("s_waitcnt vmcnt(16)" ::: "memory");
    else                       asm volatile("s_waitcnt vmcnt(24)" ::: "memory");
    __builtin_amdgcn_sched_barrier(0);  // rule #18: pin ds_reads below

    // read tile j's 8 new rows once (ds_read_b64, imm slot offsets)
#pragma unroll
    for (int i = 0; i < TT; ++i) {
      const float2* rp = (const float2*)&ring[(8 * j + i) & (RING - 1)][0];
      xv[HALO + i] = rp[lane];
    }
    // compute + store 8 outputs (dwordx2)
    float* opb = out + ((size_t)tstart * B_SZ + b) * C_SZ + c0 + 2 * lane;
#pragma unroll
    for (int o = 0; o < TT; ++o) {
      float ax = 0.f, ay = 0.f;
#pragma unroll
      for (int k = 0; k < KW; ++k) {
        ax = fmaf(wk[k], xv[o + k].x, ax);
        ay = fmaf(wk[k], xv[o + k].y, ay);
      }
      *(float2*)&opb[(size_t)o * ROWSTRIDE] = make_float2(ax, ay);
    }
    // slide window by TT (full unroll -> pure register renaming)
#pragma unroll
    for (int i = 0; i < HALO; ++i) xv[i] = xv[i + TT];
  }
}

extern "C" void kernel_launch(void* const* d_in, const int* in_sizes, int n_in,
                              void* d_out, int out_size, void* d_ws, size_t ws_size,
                              hipStream_t stream) {
  const float* x = (const float*)d_in[0];      // (T,B,C) f32
  const float* w = (const float*)d_in[1];      // (H,K) f32
  float* out = (float*)d_out;                  // (T,B,C) f32
  (void)in_sizes; (void)n_in; (void)out_size; (void)d_ws; (void)ws_size;

  dim3 grid((C_SZ / CGW) * (T_LEN / CHUNK), B_SZ);  // (256, 8) = 2048 waves
  dim3 block(64);
  lightconv_kernel<<<grid, block, 0, stream>>>(x, w, out);
}